// Round 5
// baseline (588.453 us; speedup 1.0000x reference)
//
#include <hip/hip_runtime.h>
#include <math.h>

#define N_NODES 100000
#define CDIM 128
#define E_EDGES 500000
#define NEG_SLOPE 0.2f
#define SCAN_CHUNK 1024   // 256 threads x 4 items
#define SCAN_NB ((N_NODES + SCAN_CHUNK - 1) / SCAN_CHUNK)   // 98
#define NTILES ((N_NODES + 15) / 16)                        // 6250 (exact)
#define NUNITS (2 * NTILES)                                 // (tile, half) pairs

typedef __attribute__((ext_vector_type(8))) short short8;             // 8 bf16 (MFMA frag)
typedef __attribute__((ext_vector_type(8))) unsigned short ushort8;
typedef __attribute__((ext_vector_type(4))) unsigned short u16x4;
typedef __attribute__((ext_vector_type(4))) float f32x4;

static __device__ __forceinline__ float bf2f(unsigned short u) {
    unsigned int t = ((unsigned int)u) << 16;
    return __builtin_bit_cast(float, t);
}
static __device__ __forceinline__ unsigned short f2bf(float f) {
    unsigned int u = __builtin_bit_cast(unsigned int, f);
    unsigned int r = (u + 0x7FFFu + ((u >> 16) & 1u)) >> 16;   // RNE
    return (unsigned short)r;
}
static __device__ __forceinline__ int clampi(int v, int hi) {
    return v < 0 ? 0 : (v >= hi ? hi - 1 : v);
}
static __device__ __forceinline__ float lrelu(float v) {
    return v > 0.0f ? v : NEG_SLOPE * v;
}

// direct-to-LDS 16B async copy (global_load_lds_dwordx4)
static __device__ __forceinline__ void gload_lds16(const void* g, void* l) {
    __builtin_amdgcn_global_load_lds(
        (const __attribute__((address_space(1))) void*)g,
        (__attribute__((address_space(3))) void*)l, 16, 0, 0);
}

// ---- pack all 6 fp32 128x128 W into MFMA-fragment-major bf16 ----
// chunk(kk,t): lane l (m=l&15,q=l>>4) owns W[kk*32+q*8+u][t*16+m], u=0..7.
__global__ __launch_bounds__(256)
void pack_w_all(const float* __restrict__ W0, const float* __restrict__ W1,
                const float* __restrict__ W2, const float* __restrict__ W3,
                const float* __restrict__ W4, const float* __restrict__ W5,
                unsigned short* __restrict__ Wf) {
    const float* Wp[6] = {W0, W1, W2, W3, W4, W5};
    int mi  = blockIdx.x >> 3;                       // 0..5 (block-uniform)
    int rem = ((blockIdx.x & 7) << 8) | threadIdx.x; // 0..2047
    const float* W = Wp[mi];
    int l = rem & 63, t = (rem >> 6) & 7, kk = rem >> 9;
    int m = l & 15, q = l >> 4;
    int j = t * 16 + m;
    int k0 = kk * 32 + q * 8;
    ushort8 o;
#pragma unroll
    for (int u = 0; u < 8; ++u) o[u] = f2bf(W[(k0 + u) * 128 + j]);
    *(ushort8*)(Wf + ((size_t)mi * 2048 + rem) * 8) = o;
}

// ---- fused 3-matrix projection, STREAMING form, spill-fixed v2 ----
// Round-4 finding: the unrolled h=0,1 loop let the compiler CSE the (provably
// non-aliasing) X loads back out of the loop, recreating the full round-3
// live set (~150 VGPR) against its self-chosen 128 cap -> still spilled
// (445 MB traffic, VGPR pinned 128). Rounds 1-2 proved 256-thr phase kernels
// codegen clean at 64-84 VGPR; the spill is specific to "both halves visible
// at once". Round-5 fix: the atomic steal unit IS (tile, half): u>>1 = tile,
// u&1 = h as a RUNTIME value. One X-load site, one acc[3][4], one store site
// -> live ~100 VGPR < 128, no spill structurally possible via CSE. X is read
// twice per tile but (t,0)/(t,1) are adjacent steal units -> 2nd read is an
// L2/L3 hit (no HBM FETCH delta). Full-W LDS preload + single barrier kept.
// a-op = W frag, b-op = X frag -> lane owns out[tile*16+m][t*16+q*4+r].
// XSPLIT: X fp32 hi/lo split (fp32-accurate). !XSPLIT: X bf16 (half MFMAs).
template <bool XSPLIT>
__global__ __launch_bounds__(512, 2)
void projS(const void* __restrict__ Xv,
           const unsigned short* __restrict__ Wf,    // this layer's 3 mats, frag-major
           const float* __restrict__ bias,
           unsigned short* __restrict__ Aout,
           unsigned short* __restrict__ Bout,
           unsigned short* __restrict__ Rbout,
           int* __restrict__ unitctr, int n_units, int n_rows) {
    __shared__ char wlds[98304];                   // full 3-mat W, frag-major
    const int tid  = threadIdx.x;
    const int wave = tid >> 6;
    const int lane = tid & 63;
    const int m = lane & 15, q = lane >> 4;

    // ---- one-time W preload: 6144 x 16B chunks, layout == Wf byte layout ----
#pragma unroll
    for (int c = 0; c < 12; ++c) {
        const int base = (c * 512 + wave * 64) * 16;   // wave-uniform LDS dst
        gload_lds16((const char*)Wf + base + lane * 16, wlds + base);
    }
    __syncthreads();                               // only barrier in the kernel

    int u;
    if (lane == 0) u = atomicAdd(unitctr, 1);
    u = __shfl(u, 0);

    while (u < n_units) {
        int un;                                    // prefetch next unit id
        if (lane == 0) un = atomicAdd(unitctr, 1);
        un = __shfl(un, 0);

        const int t = u >> 1;
        const int h = u & 1;                       // runtime half: no CSE across halves
        const int xrow = t * 16 + m;
        const int arow = xrow < n_rows ? xrow : n_rows - 1;

        // ---- X load + convert (8 independent 16B loads issued together) ----
        short8 xh[4], xl_[4];
#pragma unroll
        for (int kk = 0; kk < 4; ++kk) {
            if (XSPLIT) {
                const float* xp = (const float*)Xv + (size_t)arow * CDIM + kk * 32 + q * 8;
                f32x4 x0 = *(const f32x4*)xp;
                f32x4 x1 = *(const f32x4*)(xp + 4);
#pragma unroll
                for (int j = 0; j < 4; ++j) {
                    unsigned short h0 = f2bf(x0[j]);
                    xh[kk][j] = (short)h0;
                    xl_[kk][j] = (short)f2bf(x0[j] - bf2f(h0));
                    unsigned short h1 = f2bf(x1[j]);
                    xh[kk][4 + j] = (short)h1;
                    xl_[kk][4 + j] = (short)f2bf(x1[j] - bf2f(h1));
                }
            } else {
                xh[kk] = *(const short8*)((const unsigned short*)Xv +
                                          (size_t)arow * CDIM + kk * 32 + q * 8);
            }
        }

        f32x4 acc[3][4];
#pragma unroll
        for (int mi = 0; mi < 3; ++mi)
#pragma unroll
            for (int tt = 0; tt < 4; ++tt) acc[mi][tt] = (f32x4)0.0f;

#pragma unroll
        for (int kk = 0; kk < 4; ++kk) {
#pragma unroll
            for (int tt = 0; tt < 4; ++tt) {
                const int fo = ((kk * 8 + h * 4 + tt) * 64 + lane) * 16;
                short8 w0 = *(const short8*)(wlds + fo);
                short8 w1 = *(const short8*)(wlds + 32768 + fo);
                short8 w2 = *(const short8*)(wlds + 65536 + fo);
                acc[0][tt] = __builtin_amdgcn_mfma_f32_16x16x32_bf16(w0, xh[kk], acc[0][tt], 0, 0, 0);
                acc[1][tt] = __builtin_amdgcn_mfma_f32_16x16x32_bf16(w1, xh[kk], acc[1][tt], 0, 0, 0);
                acc[2][tt] = __builtin_amdgcn_mfma_f32_16x16x32_bf16(w2, xh[kk], acc[2][tt], 0, 0, 0);
                if (XSPLIT) {
                    acc[0][tt] = __builtin_amdgcn_mfma_f32_16x16x32_bf16(w0, xl_[kk], acc[0][tt], 0, 0, 0);
                    acc[1][tt] = __builtin_amdgcn_mfma_f32_16x16x32_bf16(w1, xl_[kk], acc[1][tt], 0, 0, 0);
                    acc[2][tt] = __builtin_amdgcn_mfma_f32_16x16x32_bf16(w2, xl_[kk], acc[2][tt], 0, 0, 0);
                }
            }
        }

        if (xrow < n_rows) {
#pragma unroll
            for (int tt = 0; tt < 4; ++tt) {
                const int tcol = h * 4 + tt;
                u16x4 oa, ob, orr;
                f32x4 bv = *(const f32x4*)(bias + tcol * 16 + q * 4);
#pragma unroll
                for (int r = 0; r < 4; ++r) {
                    oa[r] = f2bf(acc[0][tt][r]);
                    ob[r] = f2bf(acc[1][tt][r]);
                    orr[r] = f2bf(acc[2][tt][r] + bv[r]);
                }
                *(u16x4*)(Aout  + (size_t)xrow * CDIM + tcol * 16 + q * 4) = oa;
                *(u16x4*)(Bout  + (size_t)xrow * CDIM + tcol * 16 + q * 4) = ob;
                *(u16x4*)(Rbout + (size_t)xrow * CDIM + tcol * 16 + q * 4) = orr;
            }
        }
        u = un;
    }
}

// ======================= CSR build (once per launch) =======================
__global__ __launch_bounds__(256)
void hist_dst(const int* __restrict__ dst, int* __restrict__ cnt, int n) {
    int e = blockIdx.x * 256 + threadIdx.x;
    if (e < n) atomicAdd(&cnt[clampi(dst[e], N_NODES)], 1);
}

__global__ __launch_bounds__(256)
void scan_local(const int* __restrict__ cnt, int* __restrict__ incl,
                int* __restrict__ blockSums, int n) {
    __shared__ int lds[256];
    int t = threadIdx.x;
    int base = blockIdx.x * SCAN_CHUNK + t * 4;
    int v[4], s = 0;
#pragma unroll
    for (int j = 0; j < 4; ++j) { v[j] = (base + j < n) ? cnt[base + j] : 0; s += v[j]; }
    lds[t] = s;
    __syncthreads();
    for (int off = 1; off < 256; off <<= 1) {
        int x = (t >= off) ? lds[t - off] : 0;
        __syncthreads();
        lds[t] += x;
        __syncthreads();
    }
    int run = lds[t] - s;
#pragma unroll
    for (int j = 0; j < 4; ++j) {
        run += v[j];
        if (base + j < n) incl[base + j] = run;
    }
    if (t == 255) blockSums[blockIdx.x] = lds[255];
}

__global__ __launch_bounds__(128)
void scan_sums(int* __restrict__ blockSums, int nb) {
    __shared__ int lds[128];
    int t = threadIdx.x;
    int v = (t < nb) ? blockSums[t] : 0;
    lds[t] = v;
    __syncthreads();
    for (int off = 1; off < 128; off <<= 1) {
        int x = (t >= off) ? lds[t - off] : 0;
        __syncthreads();
        lds[t] += x;
        __syncthreads();
    }
    if (t < nb) blockSums[t] = lds[t] - v;   // exclusive
}

__global__ __launch_bounds__(256)
void add_offsets(const int* __restrict__ incl, const int* __restrict__ blockSums,
                 const int* __restrict__ cnt, int* __restrict__ rowptr,
                 int* __restrict__ cursor, int n) {
    int i = blockIdx.x * 256 + threadIdx.x;
    if (i < n) {
        int v = incl[i] + blockSums[i / SCAN_CHUNK];
        rowptr[i + 1] = v;
        cursor[i] = v - cnt[i];
    }
    if (i == 0) rowptr[0] = 0;
}

__global__ __launch_bounds__(256)
void scatter_edges(const int* __restrict__ src, const int* __restrict__ dst,
                   int* __restrict__ cursor, int* __restrict__ esrc, int n) {
    int e = blockIdx.x * 256 + threadIdx.x;
    if (e < n) {
        int d = clampi(dst[e], N_NODES);
        int p = atomicAdd(&cursor[d], 1);
        esrc[p] = clampi(src[e], N_NODES);
    }
}

// ======================= fused edge phase =======================
// 4 nodes per wave: 16-lane group per node, 8 channels per lane.
// Per edge: one ushort8 gather (16B/lane), ~30 VALU, FOUR segment shuffles
// (width 16) -- all 4 groups reduce their own edges in the SAME wave instr.
// den/acc accumulated per lane; epilogue Out[d] = relu(Rb[d] + acc/den).
template <bool BF16OUT>
__global__ __launch_bounds__(256)
void fused_edge(const int* __restrict__ rowptr, const int* __restrict__ esrc,
                const unsigned short* __restrict__ A,
                const unsigned short* __restrict__ B,
                const float* __restrict__ att,
                const unsigned short* __restrict__ Rb, void* __restrict__ Outv,
                int n_nodes) {
    const int wave = threadIdx.x >> 6;
    const int lane = threadIdx.x & 63;
    const int g    = lane >> 4;               // group 0..3 within wave
    const int i    = lane & 15;
    const int d    = (blockIdx.x * 4 + wave) * 4 + g;   // 16 nodes per block
    const bool valid = d < n_nodes;
    const int dd = valid ? d : n_nodes - 1;
    const int c0 = i * 8;

    ushort8 ub = *(const ushort8*)(B + (size_t)dd * CDIM + c0);
    float b[8], at[8];
    f32x4 at0 = *(const f32x4*)(att + c0);
    f32x4 at1 = *(const f32x4*)(att + c0 + 4);
#pragma unroll
    for (int j = 0; j < 4; ++j) {
        b[j] = bf2f(ub[j]);   b[4 + j] = bf2f(ub[4 + j]);
        at[j] = at0[j];       at[4 + j] = at1[j];
    }

    float acc[8] = {0, 0, 0, 0, 0, 0, 0, 0};
    float den = 0.0f;
    int p  = rowptr[dd];
    int p1 = valid ? rowptr[dd + 1] : p;

    for (; p < p1; ++p) {
        int s = esrc[p];
        ushort8 ua = *(const ushort8*)(A + (size_t)s * CDIM + c0);
        float a[8];
        float e = 0.0f;
#pragma unroll
        for (int j = 0; j < 8; ++j) {
            a[j] = bf2f(ua[j]);
            e += lrelu(a[j] + b[j]) * at[j];
        }
#pragma unroll
        for (int off = 8; off >= 1; off >>= 1) e += __shfl_xor(e, off, 16);
        float ee = __expf(fminf(e, 60.0f));   // |e| analytically << 60; clamp = armor
        den += ee;
#pragma unroll
        for (int j = 0; j < 8; ++j) acc[j] += ee * a[j];
    }

    if (valid) {
        float inv = 1.0f / fmaxf(den, 1e-16f);
        ushort8 rr = *(const ushort8*)(Rb + (size_t)d * CDIM + c0);
        float o[8];
#pragma unroll
        for (int j = 0; j < 8; ++j)
            o[j] = fmaxf(bf2f(rr[j]) + acc[j] * inv, 0.0f);
        if (BF16OUT) {
            ushort8 pk;
#pragma unroll
            for (int j = 0; j < 8; ++j) pk[j] = f2bf(o[j]);
            *(ushort8*)((unsigned short*)Outv + (size_t)d * CDIM + c0) = pk;
        } else {
            f32x4 o0, o1;
#pragma unroll
            for (int j = 0; j < 4; ++j) { o0[j] = o[j]; o1[j] = o[4 + j]; }
            float* op = (float*)Outv + (size_t)d * CDIM + c0;
            *(f32x4*)op = o0;
            *(f32x4*)(op + 4) = o1;
        }
    }
}

extern "C" void kernel_launch(void* const* d_in, const int* in_sizes, int n_in,
                              void* d_out, int out_size, void* d_ws, size_t ws_size,
                              hipStream_t stream) {
    const float* x     = (const float*)d_in[0];
    const int*   ei    = (const int*)d_in[1];
    const float* Wl1   = (const float*)d_in[2];
    const float* Wr1   = (const float*)d_in[3];
    const float* att1  = (const float*)d_in[4];
    const float* Wres1 = (const float*)d_in[5];
    const float* b1    = (const float*)d_in[6];
    const float* Wl2   = (const float*)d_in[7];
    const float* Wr2   = (const float*)d_in[8];
    const float* att2  = (const float*)d_in[9];
    const float* Wres2 = (const float*)d_in[10];
    const float* b2    = (const float*)d_in[11];

    const int* srcp = ei;
    const int* dstp = ei + E_EDGES;

    // ---- workspace carve (~109 MB) ----
    size_t off = 0;
    char* base = (char*)d_ws;
    auto carve = [&](size_t bytes) -> void* {
        void* q = base + off;
        off += (bytes + 255) & ~(size_t)255;
        return q;
    };
    unsigned short* Wf = (unsigned short*)carve((size_t)6 * 16384 * 2);        // 192 KB
    unsigned short* A  = (unsigned short*)carve((size_t)N_NODES * CDIM * 2);   // 25.6 MB
    unsigned short* B  = (unsigned short*)carve((size_t)N_NODES * CDIM * 2);   // 25.6 MB
    unsigned short* X1 = (unsigned short*)carve((size_t)N_NODES * CDIM * 2);   // 25.6 MB
    unsigned short* Rb = (unsigned short*)carve((size_t)N_NODES * CDIM * 2);   // 25.6 MB
    int* cnt      = (int*)carve((size_t)N_NODES * 4);
    int* rowptr   = (int*)carve((size_t)(N_NODES + 1) * 4);
    int* cursor   = (int*)carve((size_t)N_NODES * 4);
    int* esrc     = (int*)carve((size_t)E_EDGES * 4);
    int* incl     = (int*)carve((size_t)N_NODES * 4);
    int* blockSums= (int*)carve((size_t)SCAN_NB * 4);
    int* unitctr  = (int*)carve(2 * sizeof(int));
    (void)ws_size; (void)n_in; (void)in_sizes; (void)out_size;

    // ---- weight prep: all 6 mats, one launch ----
    pack_w_all<<<48, 256, 0, stream>>>(Wl1, Wr1, Wres1, Wl2, Wr2, Wres2, Wf);

    // ---- CSR build (dst-grouped), reused by both layers ----
    (void)hipMemsetAsync(cnt, 0, (size_t)N_NODES * 4, stream);
    (void)hipMemsetAsync(unitctr, 0, 2 * sizeof(int), stream);
    hist_dst<<<(E_EDGES + 255) / 256, 256, 0, stream>>>(dstp, cnt, E_EDGES);
    scan_local<<<SCAN_NB, 256, 0, stream>>>(cnt, incl, blockSums, N_NODES);
    scan_sums<<<1, 128, 0, stream>>>(blockSums, SCAN_NB);
    add_offsets<<<(N_NODES + 255) / 256, 256, 0, stream>>>(incl, blockSums, cnt,
                                                           rowptr, cursor, N_NODES);
    scatter_edges<<<(E_EDGES + 255) / 256, 256, 0, stream>>>(srcp, dstp, cursor,
                                                             esrc, E_EDGES);

    int egrid = (N_NODES + 15) / 16;   // 16 nodes per block (4 waves x 4 groups)

    // layer 1: X=x (fp32, split) -> A,B,Rb; fused_edge -> X1 (bf16)
    projS<true ><<<256, 512, 0, stream>>>(x, Wf, b1, A, B, Rb,
                                          unitctr + 0, NUNITS, N_NODES);
    fused_edge<true ><<<egrid, 256, 0, stream>>>(rowptr, esrc, A, B, att1, Rb, X1, N_NODES);
    // layer 2: X=X1 (bf16, no split) -> A,B,Rb; fused_edge -> d_out (fp32)
    projS<false><<<256, 512, 0, stream>>>(X1, Wf + (size_t)3 * 16384, b2, A, B, Rb,
                                          unitctr + 1, NUNITS, N_NODES);
    fused_edge<false><<<egrid, 256, 0, stream>>>(rowptr, esrc, A, B, att2, Rb, d_out, N_NODES);
}

// Round 6
// 323.177 us; speedup vs baseline: 1.8208x; 1.8208x over previous
//
#include <hip/hip_runtime.h>
#include <math.h>

#define N_NODES 100000
#define CDIM 128
#define E_EDGES 500000
#define NEG_SLOPE 0.2f
#define SCAN_CHUNK 1024   // 256 threads x 4 items
#define SCAN_NB ((N_NODES + SCAN_CHUNK - 1) / SCAN_CHUNK)   // 98
#define NTILES ((N_NODES + 15) / 16)                        // 6250 (exact)
#define NUNITS (2 * NTILES)                                 // (tile, half) pairs

typedef __attribute__((ext_vector_type(8))) short short8;             // 8 bf16 (MFMA frag)
typedef __attribute__((ext_vector_type(8))) unsigned short ushort8;
typedef __attribute__((ext_vector_type(4))) unsigned short u16x4;
typedef __attribute__((ext_vector_type(4))) float f32x4;

static __device__ __forceinline__ float bf2f(unsigned short u) {
    unsigned int t = ((unsigned int)u) << 16;
    return __builtin_bit_cast(float, t);
}
static __device__ __forceinline__ unsigned short f2bf(float f) {
    unsigned int u = __builtin_bit_cast(unsigned int, f);
    unsigned int r = (u + 0x7FFFu + ((u >> 16) & 1u)) >> 16;   // RNE
    return (unsigned short)r;
}
static __device__ __forceinline__ int clampi(int v, int hi) {
    return v < 0 ? 0 : (v >= hi ? hi - 1 : v);
}
static __device__ __forceinline__ float lrelu(float v) {
    return v > 0.0f ? v : NEG_SLOPE * v;
}

// direct-to-LDS 16B async copy (global_load_lds_dwordx4)
static __device__ __forceinline__ void gload_lds16(const void* g, void* l) {
    __builtin_amdgcn_global_load_lds(
        (const __attribute__((address_space(1))) void*)g,
        (__attribute__((address_space(3))) void*)l, 16, 0, 0);
}

// ---- pack all 6 fp32 128x128 W into MFMA-fragment-major bf16 ----
// chunk(kk,t): lane l (m=l&15,q=l>>4) owns W[kk*32+q*8+u][t*16+m], u=0..7.
__global__ __launch_bounds__(256)
void pack_w_all(const float* __restrict__ W0, const float* __restrict__ W1,
                const float* __restrict__ W2, const float* __restrict__ W3,
                const float* __restrict__ W4, const float* __restrict__ W5,
                unsigned short* __restrict__ Wf) {
    const float* Wp[6] = {W0, W1, W2, W3, W4, W5};
    int mi  = blockIdx.x >> 3;                       // 0..5 (block-uniform)
    int rem = ((blockIdx.x & 7) << 8) | threadIdx.x; // 0..2047
    const float* W = Wp[mi];
    int l = rem & 63, t = (rem >> 6) & 7, kk = rem >> 9;
    int m = l & 15, q = l >> 4;
    int j = t * 16 + m;
    int k0 = kk * 32 + q * 8;
    ushort8 o;
#pragma unroll
    for (int u = 0; u < 8; ++u) o[u] = f2bf(W[(k0 + u) * 128 + j]);
    *(ushort8*)(Wf + ((size_t)mi * 2048 + rem) * 8) = o;
}

// ---- fused 3-matrix projection, STREAMING form, atomic-free ----
// Round-5 finding: traffic was IDEAL (47+76 MB) yet dur stayed 177us at
// 700 GB/s / 4% Mfma -- the limiter was 25000 atomicAdds to ONE address
// from 2048 waves. Worse, the "prefetch" was nullified: un = __shfl(un,0)
// immediately after the atomicAdd forces s_waitcnt vmcnt(0) there, so every
// iteration synchronously ate the contended round-trip (~25us queue x ~6.5
// iters = 177us). r4 never showed this because it sat under its own
// spill-BW floor (445MB/2.47TB/s = 180us, exactly observed).
// Round-6 fix: work is perfectly uniform -> STATIC contiguous per-wave
// chunks, zero atomics. Wave gw of 2048 owns units [gw*U/2048,(gw+1)*U/2048)
// (6-7 each, <=5% tail). Consecutive units = both halves of one tile by the
// same wave -> 2nd X read is an L1 hit. unroll(disable) so the compiler
// can't unroll-by-2 and recreate the r4 CSE live-set spill (VGPR must stay
// ~88 < 128). Full-W 96KB LDS preload + single barrier kept.
// a-op = W frag, b-op = X frag -> lane owns out[tile*16+m][t*16+q*4+r].
// XSPLIT: X fp32 hi/lo split (fp32-accurate). !XSPLIT: X bf16 (half MFMAs).
template <bool XSPLIT>
__global__ __launch_bounds__(512, 2)
void projS(const void* __restrict__ Xv,
           const unsigned short* __restrict__ Wf,    // this layer's 3 mats, frag-major
           const float* __restrict__ bias,
           unsigned short* __restrict__ Aout,
           unsigned short* __restrict__ Bout,
           unsigned short* __restrict__ Rbout,
           int n_units, int n_rows) {
    __shared__ char wlds[98304];                   // full 3-mat W, frag-major
    const int tid  = threadIdx.x;
    const int wave = tid >> 6;
    const int lane = tid & 63;
    const int m = lane & 15, q = lane >> 4;

    // ---- one-time W preload: 6144 x 16B chunks, layout == Wf byte layout ----
#pragma unroll
    for (int c = 0; c < 12; ++c) {
        const int base = (c * 512 + wave * 64) * 16;   // wave-uniform LDS dst
        gload_lds16((const char*)Wf + base + lane * 16, wlds + base);
    }
    __syncthreads();                               // only barrier in the kernel

    // ---- static contiguous unit range for this wave (no atomics) ----
    const int NW = (int)(gridDim.x << 3);          // total waves (256*8 = 2048)
    const int gw = (int)blockIdx.x * 8 + wave;
    const int ulo = (int)(((long long)gw * n_units) / NW);
    const int uhi = (int)(((long long)(gw + 1) * n_units) / NW);

#pragma clang loop unroll(disable)
    for (int u = ulo; u < uhi; ++u) {
        const int t = u >> 1;
        const int h = u & 1;                       // runtime half: no CSE across halves
        const int xrow = t * 16 + m;
        const int arow = xrow < n_rows ? xrow : n_rows - 1;

        // ---- X load + convert (8 independent 16B loads issued together) ----
        short8 xh[4], xl_[4];
#pragma unroll
        for (int kk = 0; kk < 4; ++kk) {
            if (XSPLIT) {
                const float* xp = (const float*)Xv + (size_t)arow * CDIM + kk * 32 + q * 8;
                f32x4 x0 = *(const f32x4*)xp;
                f32x4 x1 = *(const f32x4*)(xp + 4);
#pragma unroll
                for (int j = 0; j < 4; ++j) {
                    unsigned short h0 = f2bf(x0[j]);
                    xh[kk][j] = (short)h0;
                    xl_[kk][j] = (short)f2bf(x0[j] - bf2f(h0));
                    unsigned short h1 = f2bf(x1[j]);
                    xh[kk][4 + j] = (short)h1;
                    xl_[kk][4 + j] = (short)f2bf(x1[j] - bf2f(h1));
                }
            } else {
                xh[kk] = *(const short8*)((const unsigned short*)Xv +
                                          (size_t)arow * CDIM + kk * 32 + q * 8);
            }
        }

        f32x4 acc[3][4];
#pragma unroll
        for (int mi = 0; mi < 3; ++mi)
#pragma unroll
            for (int tt = 0; tt < 4; ++tt) acc[mi][tt] = (f32x4)0.0f;

#pragma unroll
        for (int kk = 0; kk < 4; ++kk) {
#pragma unroll
            for (int tt = 0; tt < 4; ++tt) {
                const int fo = ((kk * 8 + h * 4 + tt) * 64 + lane) * 16;
                short8 w0 = *(const short8*)(wlds + fo);
                short8 w1 = *(const short8*)(wlds + 32768 + fo);
                short8 w2 = *(const short8*)(wlds + 65536 + fo);
                acc[0][tt] = __builtin_amdgcn_mfma_f32_16x16x32_bf16(w0, xh[kk], acc[0][tt], 0, 0, 0);
                acc[1][tt] = __builtin_amdgcn_mfma_f32_16x16x32_bf16(w1, xh[kk], acc[1][tt], 0, 0, 0);
                acc[2][tt] = __builtin_amdgcn_mfma_f32_16x16x32_bf16(w2, xh[kk], acc[2][tt], 0, 0, 0);
                if (XSPLIT) {
                    acc[0][tt] = __builtin_amdgcn_mfma_f32_16x16x32_bf16(w0, xl_[kk], acc[0][tt], 0, 0, 0);
                    acc[1][tt] = __builtin_amdgcn_mfma_f32_16x16x32_bf16(w1, xl_[kk], acc[1][tt], 0, 0, 0);
                    acc[2][tt] = __builtin_amdgcn_mfma_f32_16x16x32_bf16(w2, xl_[kk], acc[2][tt], 0, 0, 0);
                }
            }
        }

        if (xrow < n_rows) {
#pragma unroll
            for (int tt = 0; tt < 4; ++tt) {
                const int tcol = h * 4 + tt;
                u16x4 oa, ob, orr;
                f32x4 bv = *(const f32x4*)(bias + tcol * 16 + q * 4);
#pragma unroll
                for (int r = 0; r < 4; ++r) {
                    oa[r] = f2bf(acc[0][tt][r]);
                    ob[r] = f2bf(acc[1][tt][r]);
                    orr[r] = f2bf(acc[2][tt][r] + bv[r]);
                }
                *(u16x4*)(Aout  + (size_t)xrow * CDIM + tcol * 16 + q * 4) = oa;
                *(u16x4*)(Bout  + (size_t)xrow * CDIM + tcol * 16 + q * 4) = ob;
                *(u16x4*)(Rbout + (size_t)xrow * CDIM + tcol * 16 + q * 4) = orr;
            }
        }
    }
}

// ======================= CSR build (once per launch) =======================
__global__ __launch_bounds__(256)
void hist_dst(const int* __restrict__ dst, int* __restrict__ cnt, int n) {
    int e = blockIdx.x * 256 + threadIdx.x;
    if (e < n) atomicAdd(&cnt[clampi(dst[e], N_NODES)], 1);
}

__global__ __launch_bounds__(256)
void scan_local(const int* __restrict__ cnt, int* __restrict__ incl,
                int* __restrict__ blockSums, int n) {
    __shared__ int lds[256];
    int t = threadIdx.x;
    int base = blockIdx.x * SCAN_CHUNK + t * 4;
    int v[4], s = 0;
#pragma unroll
    for (int j = 0; j < 4; ++j) { v[j] = (base + j < n) ? cnt[base + j] : 0; s += v[j]; }
    lds[t] = s;
    __syncthreads();
    for (int off = 1; off < 256; off <<= 1) {
        int x = (t >= off) ? lds[t - off] : 0;
        __syncthreads();
        lds[t] += x;
        __syncthreads();
    }
    int run = lds[t] - s;
#pragma unroll
    for (int j = 0; j < 4; ++j) {
        run += v[j];
        if (base + j < n) incl[base + j] = run;
    }
    if (t == 255) blockSums[blockIdx.x] = lds[255];
}

__global__ __launch_bounds__(128)
void scan_sums(int* __restrict__ blockSums, int nb) {
    __shared__ int lds[128];
    int t = threadIdx.x;
    int v = (t < nb) ? blockSums[t] : 0;
    lds[t] = v;
    __syncthreads();
    for (int off = 1; off < 128; off <<= 1) {
        int x = (t >= off) ? lds[t - off] : 0;
        __syncthreads();
        lds[t] += x;
        __syncthreads();
    }
    if (t < nb) blockSums[t] = lds[t] - v;   // exclusive
}

__global__ __launch_bounds__(256)
void add_offsets(const int* __restrict__ incl, const int* __restrict__ blockSums,
                 const int* __restrict__ cnt, int* __restrict__ rowptr,
                 int* __restrict__ cursor, int n) {
    int i = blockIdx.x * 256 + threadIdx.x;
    if (i < n) {
        int v = incl[i] + blockSums[i / SCAN_CHUNK];
        rowptr[i + 1] = v;
        cursor[i] = v - cnt[i];
    }
    if (i == 0) rowptr[0] = 0;
}

__global__ __launch_bounds__(256)
void scatter_edges(const int* __restrict__ src, const int* __restrict__ dst,
                   int* __restrict__ cursor, int* __restrict__ esrc, int n) {
    int e = blockIdx.x * 256 + threadIdx.x;
    if (e < n) {
        int d = clampi(dst[e], N_NODES);
        int p = atomicAdd(&cursor[d], 1);
        esrc[p] = clampi(src[e], N_NODES);
    }
}

// ======================= fused edge phase =======================
// 4 nodes per wave: 16-lane group per node, 8 channels per lane.
// Per edge: one ushort8 gather (16B/lane), ~30 VALU, FOUR segment shuffles
// (width 16) -- all 4 groups reduce their own edges in the SAME wave instr.
// den/acc accumulated per lane; epilogue Out[d] = relu(Rb[d] + acc/den).
template <bool BF16OUT>
__global__ __launch_bounds__(256)
void fused_edge(const int* __restrict__ rowptr, const int* __restrict__ esrc,
                const unsigned short* __restrict__ A,
                const unsigned short* __restrict__ B,
                const float* __restrict__ att,
                const unsigned short* __restrict__ Rb, void* __restrict__ Outv,
                int n_nodes) {
    const int wave = threadIdx.x >> 6;
    const int lane = threadIdx.x & 63;
    const int g    = lane >> 4;               // group 0..3 within wave
    const int i    = lane & 15;
    const int d    = (blockIdx.x * 4 + wave) * 4 + g;   // 16 nodes per block
    const bool valid = d < n_nodes;
    const int dd = valid ? d : n_nodes - 1;
    const int c0 = i * 8;

    ushort8 ub = *(const ushort8*)(B + (size_t)dd * CDIM + c0);
    float b[8], at[8];
    f32x4 at0 = *(const f32x4*)(att + c0);
    f32x4 at1 = *(const f32x4*)(att + c0 + 4);
#pragma unroll
    for (int j = 0; j < 4; ++j) {
        b[j] = bf2f(ub[j]);   b[4 + j] = bf2f(ub[4 + j]);
        at[j] = at0[j];       at[4 + j] = at1[j];
    }

    float acc[8] = {0, 0, 0, 0, 0, 0, 0, 0};
    float den = 0.0f;
    int p  = rowptr[dd];
    int p1 = valid ? rowptr[dd + 1] : p;

    for (; p < p1; ++p) {
        int s = esrc[p];
        ushort8 ua = *(const ushort8*)(A + (size_t)s * CDIM + c0);
        float a[8];
        float e = 0.0f;
#pragma unroll
        for (int j = 0; j < 8; ++j) {
            a[j] = bf2f(ua[j]);
            e += lrelu(a[j] + b[j]) * at[j];
        }
#pragma unroll
        for (int off = 8; off >= 1; off >>= 1) e += __shfl_xor(e, off, 16);
        float ee = __expf(fminf(e, 60.0f));   // |e| analytically << 60; clamp = armor
        den += ee;
#pragma unroll
        for (int j = 0; j < 8; ++j) acc[j] += ee * a[j];
    }

    if (valid) {
        float inv = 1.0f / fmaxf(den, 1e-16f);
        ushort8 rr = *(const ushort8*)(Rb + (size_t)d * CDIM + c0);
        float o[8];
#pragma unroll
        for (int j = 0; j < 8; ++j)
            o[j] = fmaxf(bf2f(rr[j]) + acc[j] * inv, 0.0f);
        if (BF16OUT) {
            ushort8 pk;
#pragma unroll
            for (int j = 0; j < 8; ++j) pk[j] = f2bf(o[j]);
            *(ushort8*)((unsigned short*)Outv + (size_t)d * CDIM + c0) = pk;
        } else {
            f32x4 o0, o1;
#pragma unroll
            for (int j = 0; j < 4; ++j) { o0[j] = o[j]; o1[j] = o[4 + j]; }
            float* op = (float*)Outv + (size_t)d * CDIM + c0;
            *(f32x4*)op = o0;
            *(f32x4*)(op + 4) = o1;
        }
    }
}

extern "C" void kernel_launch(void* const* d_in, const int* in_sizes, int n_in,
                              void* d_out, int out_size, void* d_ws, size_t ws_size,
                              hipStream_t stream) {
    const float* x     = (const float*)d_in[0];
    const int*   ei    = (const int*)d_in[1];
    const float* Wl1   = (const float*)d_in[2];
    const float* Wr1   = (const float*)d_in[3];
    const float* att1  = (const float*)d_in[4];
    const float* Wres1 = (const float*)d_in[5];
    const float* b1    = (const float*)d_in[6];
    const float* Wl2   = (const float*)d_in[7];
    const float* Wr2   = (const float*)d_in[8];
    const float* att2  = (const float*)d_in[9];
    const float* Wres2 = (const float*)d_in[10];
    const float* b2    = (const float*)d_in[11];

    const int* srcp = ei;
    const int* dstp = ei + E_EDGES;

    // ---- workspace carve (~109 MB) ----
    size_t off = 0;
    char* base = (char*)d_ws;
    auto carve = [&](size_t bytes) -> void* {
        void* q = base + off;
        off += (bytes + 255) & ~(size_t)255;
        return q;
    };
    unsigned short* Wf = (unsigned short*)carve((size_t)6 * 16384 * 2);        // 192 KB
    unsigned short* A  = (unsigned short*)carve((size_t)N_NODES * CDIM * 2);   // 25.6 MB
    unsigned short* B  = (unsigned short*)carve((size_t)N_NODES * CDIM * 2);   // 25.6 MB
    unsigned short* X1 = (unsigned short*)carve((size_t)N_NODES * CDIM * 2);   // 25.6 MB
    unsigned short* Rb = (unsigned short*)carve((size_t)N_NODES * CDIM * 2);   // 25.6 MB
    int* cnt      = (int*)carve((size_t)N_NODES * 4);
    int* rowptr   = (int*)carve((size_t)(N_NODES + 1) * 4);
    int* cursor   = (int*)carve((size_t)N_NODES * 4);
    int* esrc     = (int*)carve((size_t)E_EDGES * 4);
    int* incl     = (int*)carve((size_t)N_NODES * 4);
    int* blockSums= (int*)carve((size_t)SCAN_NB * 4);
    (void)ws_size; (void)n_in; (void)in_sizes; (void)out_size;

    // ---- weight prep: all 6 mats, one launch ----
    pack_w_all<<<48, 256, 0, stream>>>(Wl1, Wr1, Wres1, Wl2, Wr2, Wres2, Wf);

    // ---- CSR build (dst-grouped), reused by both layers ----
    (void)hipMemsetAsync(cnt, 0, (size_t)N_NODES * 4, stream);
    hist_dst<<<(E_EDGES + 255) / 256, 256, 0, stream>>>(dstp, cnt, E_EDGES);
    scan_local<<<SCAN_NB, 256, 0, stream>>>(cnt, incl, blockSums, N_NODES);
    scan_sums<<<1, 128, 0, stream>>>(blockSums, SCAN_NB);
    add_offsets<<<(N_NODES + 255) / 256, 256, 0, stream>>>(incl, blockSums, cnt,
                                                           rowptr, cursor, N_NODES);
    scatter_edges<<<(E_EDGES + 255) / 256, 256, 0, stream>>>(srcp, dstp, cursor,
                                                             esrc, E_EDGES);

    int egrid = (N_NODES + 15) / 16;   // 16 nodes per block (4 waves x 4 groups)

    // layer 1: X=x (fp32, split) -> A,B,Rb; fused_edge -> X1 (bf16)
    projS<true ><<<256, 512, 0, stream>>>(x, Wf, b1, A, B, Rb, NUNITS, N_NODES);
    fused_edge<true ><<<egrid, 256, 0, stream>>>(rowptr, esrc, A, B, att1, Rb, X1, N_NODES);
    // layer 2: X=X1 (bf16, no split) -> A,B,Rb; fused_edge -> d_out (fp32)
    projS<false><<<256, 512, 0, stream>>>(X1, Wf + (size_t)3 * 16384, b2, A, B, Rb, NUNITS, N_NODES);
    fused_edge<false><<<egrid, 256, 0, stream>>>(rowptr, esrc, A, B, att2, Rb, d_out, N_NODES);
}

// Round 7
// 323.033 us; speedup vs baseline: 1.8217x; 1.0004x over previous
//
#include <hip/hip_runtime.h>
#include <math.h>

#define N_NODES 100000
#define CDIM 128
#define E_EDGES 500000
#define NEG_SLOPE 0.2f
#define SCAN_CHUNK 1024   // 256 threads x 4 items
#define SCAN_NB ((N_NODES + SCAN_CHUNK - 1) / SCAN_CHUNK)   // 98
#define NTILES ((N_NODES + 15) / 16)                        // 6250 (exact)
#define NUNITS (2 * NTILES)                                 // (tile, half) pairs

typedef __attribute__((ext_vector_type(8))) short short8;             // 8 bf16 (MFMA frag)
typedef __attribute__((ext_vector_type(8))) unsigned short ushort8;
typedef __attribute__((ext_vector_type(4))) unsigned short u16x4;
typedef __attribute__((ext_vector_type(4))) float f32x4;

static __device__ __forceinline__ float bf2f(unsigned short u) {
    unsigned int t = ((unsigned int)u) << 16;
    return __builtin_bit_cast(float, t);
}
static __device__ __forceinline__ unsigned short f2bf(float f) {
    unsigned int u = __builtin_bit_cast(unsigned int, f);
    unsigned int r = (u + 0x7FFFu + ((u >> 16) & 1u)) >> 16;   // RNE
    return (unsigned short)r;
}
static __device__ __forceinline__ int clampi(int v, int hi) {
    return v < 0 ? 0 : (v >= hi ? hi - 1 : v);
}
static __device__ __forceinline__ float lrelu(float v) {
    return v > 0.0f ? v : NEG_SLOPE * v;
}

// direct-to-LDS 16B async copy (global_load_lds_dwordx4)
static __device__ __forceinline__ void gload_lds16(const void* g, void* l) {
    __builtin_amdgcn_global_load_lds(
        (const __attribute__((address_space(1))) void*)g,
        (__attribute__((address_space(3))) void*)l, 16, 0, 0);
}

// ---- pack all 6 fp32 128x128 W into MFMA-fragment-major bf16 ----
// chunk(kk,t): lane l (m=l&15,q=l>>4) owns W[kk*32+q*8+u][t*16+m], u=0..7.
__global__ __launch_bounds__(256)
void pack_w_all(const float* __restrict__ W0, const float* __restrict__ W1,
                const float* __restrict__ W2, const float* __restrict__ W3,
                const float* __restrict__ W4, const float* __restrict__ W5,
                unsigned short* __restrict__ Wf) {
    const float* Wp[6] = {W0, W1, W2, W3, W4, W5};
    int mi  = blockIdx.x >> 3;                       // 0..5 (block-uniform)
    int rem = ((blockIdx.x & 7) << 8) | threadIdx.x; // 0..2047
    const float* W = Wp[mi];
    int l = rem & 63, t = (rem >> 6) & 7, kk = rem >> 9;
    int m = l & 15, q = l >> 4;
    int j = t * 16 + m;
    int k0 = kk * 32 + q * 8;
    ushort8 o;
#pragma unroll
    for (int u = 0; u < 8; ++u) o[u] = f2bf(W[(k0 + u) * 128 + j]);
    *(ushort8*)(Wf + ((size_t)mi * 2048 + rem) * 8) = o;
}

// ---- fused 3-matrix projection, STREAMING form, atomic-free, 16-wave ----
// Round-6 finding: atomic removal fixed the serialization (177->59us, VGPR 88,
// traffic ideal) but projS is still 3x the HBM floor at 1.95 TB/s with
// OccupancyPercent 13: 96KB LDS -> 1 block/CU x 8 waves = 2 waves/SIMD, and
// unroll(disable) exposes each unit's X-load latency serially -- TLP-starved.
// Round-7 fix: 1024 threads/block (16 waves in the ONE resident block), grid
// 256 -> 4 waves/SIMD, 2x latency hiding, no register-pressure change
// (VGPR 88 << 128 cap @ 4 waves/EU). W preload = 6 sweeps of 16KB. Static
// chunks over 4096 waves (~3 units each). Full-W LDS + single barrier kept.
// a-op = W frag, b-op = X frag -> lane owns out[tile*16+m][t*16+q*4+r].
// XSPLIT: X fp32 hi/lo split (fp32-accurate). !XSPLIT: X bf16 (half MFMAs).
template <bool XSPLIT>
__global__ __launch_bounds__(1024, 4)
void projS(const void* __restrict__ Xv,
           const unsigned short* __restrict__ Wf,    // this layer's 3 mats, frag-major
           const float* __restrict__ bias,
           unsigned short* __restrict__ Aout,
           unsigned short* __restrict__ Bout,
           unsigned short* __restrict__ Rbout,
           int n_units, int n_rows) {
    __shared__ char wlds[98304];                   // full 3-mat W, frag-major
    const int tid  = threadIdx.x;
    const int wave = tid >> 6;                     // 0..15
    const int lane = tid & 63;
    const int m = lane & 15, q = lane >> 4;

    // ---- one-time W preload: 6 sweeps x 16KB (1024 thr x 16B), linear ----
#pragma unroll
    for (int c = 0; c < 6; ++c) {
        const int base = c * 16384 + wave * 1024;  // wave-uniform LDS dst
        gload_lds16((const char*)Wf + base + lane * 16, wlds + base);
    }
    __syncthreads();                               // only barrier in the kernel

    // ---- static contiguous unit range for this wave (no atomics) ----
    const int NW = (int)(gridDim.x << 4);          // total waves (256*16 = 4096)
    const int gw = (int)blockIdx.x * 16 + wave;
    const int ulo = (int)(((long long)gw * n_units) / NW);
    const int uhi = (int)(((long long)(gw + 1) * n_units) / NW);

#pragma clang loop unroll(disable)
    for (int u = ulo; u < uhi; ++u) {
        const int t = u >> 1;
        const int h = u & 1;                       // runtime half: no CSE across halves
        const int xrow = t * 16 + m;
        const int arow = xrow < n_rows ? xrow : n_rows - 1;

        // ---- X load + convert (8 independent 16B loads issued together) ----
        short8 xh[4], xl_[4];
#pragma unroll
        for (int kk = 0; kk < 4; ++kk) {
            if (XSPLIT) {
                const float* xp = (const float*)Xv + (size_t)arow * CDIM + kk * 32 + q * 8;
                f32x4 x0 = *(const f32x4*)xp;
                f32x4 x1 = *(const f32x4*)(xp + 4);
#pragma unroll
                for (int j = 0; j < 4; ++j) {
                    unsigned short h0 = f2bf(x0[j]);
                    xh[kk][j] = (short)h0;
                    xl_[kk][j] = (short)f2bf(x0[j] - bf2f(h0));
                    unsigned short h1 = f2bf(x1[j]);
                    xh[kk][4 + j] = (short)h1;
                    xl_[kk][4 + j] = (short)f2bf(x1[j] - bf2f(h1));
                }
            } else {
                xh[kk] = *(const short8*)((const unsigned short*)Xv +
                                          (size_t)arow * CDIM + kk * 32 + q * 8);
            }
        }

        f32x4 acc[3][4];
#pragma unroll
        for (int mi = 0; mi < 3; ++mi)
#pragma unroll
            for (int tt = 0; tt < 4; ++tt) acc[mi][tt] = (f32x4)0.0f;

#pragma unroll
        for (int kk = 0; kk < 4; ++kk) {
#pragma unroll
            for (int tt = 0; tt < 4; ++tt) {
                const int fo = ((kk * 8 + h * 4 + tt) * 64 + lane) * 16;
                short8 w0 = *(const short8*)(wlds + fo);
                short8 w1 = *(const short8*)(wlds + 32768 + fo);
                short8 w2 = *(const short8*)(wlds + 65536 + fo);
                acc[0][tt] = __builtin_amdgcn_mfma_f32_16x16x32_bf16(w0, xh[kk], acc[0][tt], 0, 0, 0);
                acc[1][tt] = __builtin_amdgcn_mfma_f32_16x16x32_bf16(w1, xh[kk], acc[1][tt], 0, 0, 0);
                acc[2][tt] = __builtin_amdgcn_mfma_f32_16x16x32_bf16(w2, xh[kk], acc[2][tt], 0, 0, 0);
                if (XSPLIT) {
                    acc[0][tt] = __builtin_amdgcn_mfma_f32_16x16x32_bf16(w0, xl_[kk], acc[0][tt], 0, 0, 0);
                    acc[1][tt] = __builtin_amdgcn_mfma_f32_16x16x32_bf16(w1, xl_[kk], acc[1][tt], 0, 0, 0);
                    acc[2][tt] = __builtin_amdgcn_mfma_f32_16x16x32_bf16(w2, xl_[kk], acc[2][tt], 0, 0, 0);
                }
            }
        }

        if (xrow < n_rows) {
#pragma unroll
            for (int tt = 0; tt < 4; ++tt) {
                const int tcol = h * 4 + tt;
                u16x4 oa, ob, orr;
                f32x4 bv = *(const f32x4*)(bias + tcol * 16 + q * 4);
#pragma unroll
                for (int r = 0; r < 4; ++r) {
                    oa[r] = f2bf(acc[0][tt][r]);
                    ob[r] = f2bf(acc[1][tt][r]);
                    orr[r] = f2bf(acc[2][tt][r] + bv[r]);
                }
                *(u16x4*)(Aout  + (size_t)xrow * CDIM + tcol * 16 + q * 4) = oa;
                *(u16x4*)(Bout  + (size_t)xrow * CDIM + tcol * 16 + q * 4) = ob;
                *(u16x4*)(Rbout + (size_t)xrow * CDIM + tcol * 16 + q * 4) = orr;
            }
        }
    }
}

// ======================= CSR build (once per launch) =======================
__global__ __launch_bounds__(256)
void hist_dst(const int* __restrict__ dst, int* __restrict__ cnt, int n) {
    int e = blockIdx.x * 256 + threadIdx.x;
    if (e < n) atomicAdd(&cnt[clampi(dst[e], N_NODES)], 1);
}

__global__ __launch_bounds__(256)
void scan_local(const int* __restrict__ cnt, int* __restrict__ incl,
                int* __restrict__ blockSums, int n) {
    __shared__ int lds[256];
    int t = threadIdx.x;
    int base = blockIdx.x * SCAN_CHUNK + t * 4;
    int v[4], s = 0;
#pragma unroll
    for (int j = 0; j < 4; ++j) { v[j] = (base + j < n) ? cnt[base + j] : 0; s += v[j]; }
    lds[t] = s;
    __syncthreads();
    for (int off = 1; off < 256; off <<= 1) {
        int x = (t >= off) ? lds[t - off] : 0;
        __syncthreads();
        lds[t] += x;
        __syncthreads();
    }
    int run = lds[t] - s;
#pragma unroll
    for (int j = 0; j < 4; ++j) {
        run += v[j];
        if (base + j < n) incl[base + j] = run;
    }
    if (t == 255) blockSums[blockIdx.x] = lds[255];
}

__global__ __launch_bounds__(128)
void scan_sums(int* __restrict__ blockSums, int nb) {
    __shared__ int lds[128];
    int t = threadIdx.x;
    int v = (t < nb) ? blockSums[t] : 0;
    lds[t] = v;
    __syncthreads();
    for (int off = 1; off < 128; off <<= 1) {
        int x = (t >= off) ? lds[t - off] : 0;
        __syncthreads();
        lds[t] += x;
        __syncthreads();
    }
    if (t < nb) blockSums[t] = lds[t] - v;   // exclusive
}

__global__ __launch_bounds__(256)
void add_offsets(const int* __restrict__ incl, const int* __restrict__ blockSums,
                 const int* __restrict__ cnt, int* __restrict__ rowptr,
                 int* __restrict__ cursor, int n) {
    int i = blockIdx.x * 256 + threadIdx.x;
    if (i < n) {
        int v = incl[i] + blockSums[i / SCAN_CHUNK];
        rowptr[i + 1] = v;
        cursor[i] = v - cnt[i];
    }
    if (i == 0) rowptr[0] = 0;
}

__global__ __launch_bounds__(256)
void scatter_edges(const int* __restrict__ src, const int* __restrict__ dst,
                   int* __restrict__ cursor, int* __restrict__ esrc, int n) {
    int e = blockIdx.x * 256 + threadIdx.x;
    if (e < n) {
        int d = clampi(dst[e], N_NODES);
        int p = atomicAdd(&cursor[d], 1);
        esrc[p] = clampi(src[e], N_NODES);
    }
}

// ======================= fused edge phase =======================
// 4 nodes per wave: 16-lane group per node, 8 channels per lane.
// Per edge: one ushort8 gather (16B/lane), ~30 VALU, FOUR segment shuffles
// (width 16) -- all 4 groups reduce their own edges in the SAME wave instr.
// den/acc accumulated per lane; epilogue Out[d] = relu(Rb[d] + acc/den).
template <bool BF16OUT>
__global__ __launch_bounds__(256)
void fused_edge(const int* __restrict__ rowptr, const int* __restrict__ esrc,
                const unsigned short* __restrict__ A,
                const unsigned short* __restrict__ B,
                const float* __restrict__ att,
                const unsigned short* __restrict__ Rb, void* __restrict__ Outv,
                int n_nodes) {
    const int wave = threadIdx.x >> 6;
    const int lane = threadIdx.x & 63;
    const int g    = lane >> 4;               // group 0..3 within wave
    const int i    = lane & 15;
    const int d    = (blockIdx.x * 4 + wave) * 4 + g;   // 16 nodes per block
    const bool valid = d < n_nodes;
    const int dd = valid ? d : n_nodes - 1;
    const int c0 = i * 8;

    ushort8 ub = *(const ushort8*)(B + (size_t)dd * CDIM + c0);
    float b[8], at[8];
    f32x4 at0 = *(const f32x4*)(att + c0);
    f32x4 at1 = *(const f32x4*)(att + c0 + 4);
#pragma unroll
    for (int j = 0; j < 4; ++j) {
        b[j] = bf2f(ub[j]);   b[4 + j] = bf2f(ub[4 + j]);
        at[j] = at0[j];       at[4 + j] = at1[j];
    }

    float acc[8] = {0, 0, 0, 0, 0, 0, 0, 0};
    float den = 0.0f;
    int p  = rowptr[dd];
    int p1 = valid ? rowptr[dd + 1] : p;

    for (; p < p1; ++p) {
        int s = esrc[p];
        ushort8 ua = *(const ushort8*)(A + (size_t)s * CDIM + c0);
        float a[8];
        float e = 0.0f;
#pragma unroll
        for (int j = 0; j < 8; ++j) {
            a[j] = bf2f(ua[j]);
            e += lrelu(a[j] + b[j]) * at[j];
        }
#pragma unroll
        for (int off = 8; off >= 1; off >>= 1) e += __shfl_xor(e, off, 16);
        float ee = __expf(fminf(e, 60.0f));   // |e| analytically << 60; clamp = armor
        den += ee;
#pragma unroll
        for (int j = 0; j < 8; ++j) acc[j] += ee * a[j];
    }

    if (valid) {
        float inv = 1.0f / fmaxf(den, 1e-16f);
        ushort8 rr = *(const ushort8*)(Rb + (size_t)d * CDIM + c0);
        float o[8];
#pragma unroll
        for (int j = 0; j < 8; ++j)
            o[j] = fmaxf(bf2f(rr[j]) + acc[j] * inv, 0.0f);
        if (BF16OUT) {
            ushort8 pk;
#pragma unroll
            for (int j = 0; j < 8; ++j) pk[j] = f2bf(o[j]);
            *(ushort8*)((unsigned short*)Outv + (size_t)d * CDIM + c0) = pk;
        } else {
            f32x4 o0, o1;
#pragma unroll
            for (int j = 0; j < 4; ++j) { o0[j] = o[j]; o1[j] = o[4 + j]; }
            float* op = (float*)Outv + (size_t)d * CDIM + c0;
            *(f32x4*)op = o0;
            *(f32x4*)(op + 4) = o1;
        }
    }
}

extern "C" void kernel_launch(void* const* d_in, const int* in_sizes, int n_in,
                              void* d_out, int out_size, void* d_ws, size_t ws_size,
                              hipStream_t stream) {
    const float* x     = (const float*)d_in[0];
    const int*   ei    = (const int*)d_in[1];
    const float* Wl1   = (const float*)d_in[2];
    const float* Wr1   = (const float*)d_in[3];
    const float* att1  = (const float*)d_in[4];
    const float* Wres1 = (const float*)d_in[5];
    const float* b1    = (const float*)d_in[6];
    const float* Wl2   = (const float*)d_in[7];
    const float* Wr2   = (const float*)d_in[8];
    const float* att2  = (const float*)d_in[9];
    const float* Wres2 = (const float*)d_in[10];
    const float* b2    = (const float*)d_in[11];

    const int* srcp = ei;
    const int* dstp = ei + E_EDGES;

    // ---- workspace carve (~109 MB) ----
    size_t off = 0;
    char* base = (char*)d_ws;
    auto carve = [&](size_t bytes) -> void* {
        void* q = base + off;
        off += (bytes + 255) & ~(size_t)255;
        return q;
    };
    unsigned short* Wf = (unsigned short*)carve((size_t)6 * 16384 * 2);        // 192 KB
    unsigned short* A  = (unsigned short*)carve((size_t)N_NODES * CDIM * 2);   // 25.6 MB
    unsigned short* B  = (unsigned short*)carve((size_t)N_NODES * CDIM * 2);   // 25.6 MB
    unsigned short* X1 = (unsigned short*)carve((size_t)N_NODES * CDIM * 2);   // 25.6 MB
    unsigned short* Rb = (unsigned short*)carve((size_t)N_NODES * CDIM * 2);   // 25.6 MB
    int* cnt      = (int*)carve((size_t)N_NODES * 4);
    int* rowptr   = (int*)carve((size_t)(N_NODES + 1) * 4);
    int* cursor   = (int*)carve((size_t)N_NODES * 4);
    int* esrc     = (int*)carve((size_t)E_EDGES * 4);
    int* incl     = (int*)carve((size_t)N_NODES * 4);
    int* blockSums= (int*)carve((size_t)SCAN_NB * 4);
    (void)ws_size; (void)n_in; (void)in_sizes; (void)out_size;

    // ---- weight prep: all 6 mats, one launch ----
    pack_w_all<<<48, 256, 0, stream>>>(Wl1, Wr1, Wres1, Wl2, Wr2, Wres2, Wf);

    // ---- CSR build (dst-grouped), reused by both layers ----
    (void)hipMemsetAsync(cnt, 0, (size_t)N_NODES * 4, stream);
    hist_dst<<<(E_EDGES + 255) / 256, 256, 0, stream>>>(dstp, cnt, E_EDGES);
    scan_local<<<SCAN_NB, 256, 0, stream>>>(cnt, incl, blockSums, N_NODES);
    scan_sums<<<1, 128, 0, stream>>>(blockSums, SCAN_NB);
    add_offsets<<<(N_NODES + 255) / 256, 256, 0, stream>>>(incl, blockSums, cnt,
                                                           rowptr, cursor, N_NODES);
    scatter_edges<<<(E_EDGES + 255) / 256, 256, 0, stream>>>(srcp, dstp, cursor,
                                                             esrc, E_EDGES);

    int egrid = (N_NODES + 15) / 16;   // 16 nodes per block (4 waves x 4 groups)

    // layer 1: X=x (fp32, split) -> A,B,Rb; fused_edge -> X1 (bf16)
    projS<true ><<<256, 1024, 0, stream>>>(x, Wf, b1, A, B, Rb, NUNITS, N_NODES);
    fused_edge<true ><<<egrid, 256, 0, stream>>>(rowptr, esrc, A, B, att1, Rb, X1, N_NODES);
    // layer 2: X=X1 (bf16, no split) -> A,B,Rb; fused_edge -> d_out (fp32)
    projS<false><<<256, 1024, 0, stream>>>(X1, Wf + (size_t)3 * 16384, b2, A, B, Rb, NUNITS, N_NODES);
    fused_edge<false><<<egrid, 256, 0, stream>>>(rowptr, esrc, A, B, att2, Rb, d_out, N_NODES);
}